// Round 6
// baseline (413.250 us; speedup 1.0000x reference)
//
#include <hip/hip_runtime.h>
#include <cstdint>
#include <cstddef>

// SelfAttention: B=8, S=2048, D=512, fp32 in/out.
// R6: flash rewrite — 512 threads (8 waves), in-block split-K (2 groups of 4
// waves over 1024 keys each, merged via LDS), transposed S^T/O^T compute so
// softmax state is per-lane scalar, xor-16 LDS swizzle (conflict-free b128).
// ws: [qh 16M][kh 16M][vh 16M][vt 16M (xh aliases)][Wt 1.5M] = 65.5 MiB.

#define SEQ 2048
#define DIM 512
#define NB 8
#define BSZ (NB * SEQ)

typedef __attribute__((ext_vector_type(8))) _Float16 half8;
typedef __attribute__((ext_vector_type(4))) float f32x4;

__device__ __forceinline__ unsigned short f2h(float f) {
  _Float16 h = (_Float16)f;
  return __builtin_bit_cast(unsigned short, h);
}
__device__ __forceinline__ half8 ld_frag(const unsigned short* p) {
  return *(const half8*)(const void*)p;
}
__device__ __forceinline__ void gl_lds16(const unsigned short* g, unsigned short* l) {
  __builtin_amdgcn_global_load_lds(
      (__attribute__((address_space(1))) void*)g,
      (__attribute__((address_space(3))) void*)l, 16, 0, 0);
}

// ---------------------------------------------------------------------------
__global__ __launch_bounds__(256) void cvt_x_kernel(
    const float* __restrict__ X, unsigned short* __restrict__ xh)
{
  size_t i0 = ((size_t)blockIdx.x * 256 + threadIdx.x) * 8;
  float4 a = *(const float4*)&X[i0];
  float4 b = *(const float4*)&X[i0 + 4];
  ushort4 o0; o0.x = f2h(a.x); o0.y = f2h(a.y); o0.z = f2h(a.z); o0.w = f2h(a.w);
  ushort4 o1; o1.x = f2h(b.x); o1.y = f2h(b.y); o1.z = f2h(b.z); o1.w = f2h(b.w);
  *(ushort4*)&xh[i0] = o0;
  *(ushort4*)&xh[i0 + 4] = o1;
}

// ---------------------------------------------------------------------------
__global__ __launch_bounds__(256) void cvt_w_kernel(
    const float* __restrict__ Wq, const float* __restrict__ Wk,
    const float* __restrict__ Wv, unsigned short* __restrict__ Wt)
{
  const int z = blockIdx.z;
  const float* W = (z == 0) ? Wq : (z == 1) ? Wk : Wv;
  unsigned short* out = Wt + (size_t)z * DIM * DIM;
  const int k0 = blockIdx.x * 64, n0 = blockIdx.y * 64;
  const int t = threadIdx.x;
  __shared__ unsigned short tl[64 * 72];
#pragma unroll
  for (int i = 0; i < 4; i++) {
    int f = t + 256 * i;
    int kr = f >> 4, c4 = (f & 15) * 4;
    float4 v = *(const float4*)&W[(size_t)(k0 + kr) * DIM + n0 + c4];
    tl[(c4 + 0) * 72 + kr] = f2h(v.x);
    tl[(c4 + 1) * 72 + kr] = f2h(v.y);
    tl[(c4 + 2) * 72 + kr] = f2h(v.z);
    tl[(c4 + 3) * 72 + kr] = f2h(v.w);
  }
  __syncthreads();
#pragma unroll
  for (int i = 0; i < 2; i++) {
    int f = t + 256 * i;
    int nr = f >> 3, k8 = (f & 7) * 8;
    *(uint4*)&out[(size_t)(n0 + nr) * DIM + k0 + k8] = *(const uint4*)&tl[nr * 72 + k8];
  }
}

// ---------------------------------------------------------------------------
// proj (unchanged, validated): qkv[z] = fp16(xh @ Wt[z]^T + b[z]).
// ---------------------------------------------------------------------------
__global__ __launch_bounds__(256) void proj_kernel(
    const unsigned short* __restrict__ xh, const unsigned short* __restrict__ Wt,
    const float* __restrict__ bq, const float* __restrict__ bk,
    const float* __restrict__ bv, unsigned short* __restrict__ outbase)
{
  const int z = blockIdx.z;
  const unsigned short* Wz = Wt + (size_t)z * DIM * DIM;
  const float* bias = (z == 0) ? bq : (z == 1) ? bk : bv;
  unsigned short* out = outbase + (size_t)z * BSZ * DIM;
  const int m0 = blockIdx.x * 128, n0 = blockIdx.y * 128;
  const int t = threadIdx.x, lane = t & 63, wave = t >> 6;
  const int wrow = (wave >> 1) * 64, wcol = (wave & 1) * 64;
  const int lr = lane & 15, lq = (lane >> 4) * 8;

  __shared__ unsigned short sm[128 * 132];
  unsigned short* As = sm;
  unsigned short* Bs = sm + 128 * 64;

  f32x4 acc[4][4];
  const f32x4 zero = {0.f, 0.f, 0.f, 0.f};
#pragma unroll
  for (int r = 0; r < 4; r++)
#pragma unroll
    for (int c = 0; c < 4; c++) acc[r][c] = zero;

  for (int k0 = 0; k0 < DIM; k0 += 64) {
    __syncthreads();
#pragma unroll
    for (int i = 0; i < 4; i++) {
      int f = t + 256 * i;
      int row = f >> 3, c8 = (f & 7) * 8;
      gl_lds16(&xh[(size_t)(m0 + row) * DIM + k0 + c8], &As[i * 2048 + wave * 512]);
      gl_lds16(&Wz[(size_t)(n0 + row) * DIM + k0 + c8], &Bs[i * 2048 + wave * 512]);
    }
    __syncthreads();
#pragma unroll
    for (int kk = 0; kk < 64; kk += 32) {
      half8 a[4], b[4];
#pragma unroll
      for (int r = 0; r < 4; r++) a[r] = ld_frag(&As[(wrow + 16 * r + lr) * 64 + kk + lq]);
#pragma unroll
      for (int c = 0; c < 4; c++) b[c] = ld_frag(&Bs[(wcol + 16 * c + lr) * 64 + kk + lq]);
#pragma unroll
      for (int r = 0; r < 4; r++)
#pragma unroll
        for (int c = 0; c < 4; c++)
          acc[r][c] = __builtin_amdgcn_mfma_f32_16x16x32_f16(a[r], b[c], acc[r][c], 0, 0, 0);
    }
  }
  __syncthreads();
#pragma unroll
  for (int c = 0; c < 4; c++) {
    float bb = bias[n0 + wcol + 16 * c + lr];
#pragma unroll
    for (int r = 0; r < 4; r++)
#pragma unroll
      for (int e = 0; e < 4; e++)
        sm[(wrow + 16 * r + (lane >> 4) * 4 + e) * 132 + wcol + 16 * c + lr] =
            f2h(acc[r][c][e] + bb);
  }
  __syncthreads();
#pragma unroll
  for (int i = 0; i < 8; i++) {
    int f = t + 256 * i;
    int row = f >> 4, c8 = (f & 15) * 8;
    *(uint4*)&out[(size_t)(m0 + row) * DIM + n0 + c8] = *(const uint4*)&sm[row * 132 + c8];
  }
}

// ---------------------------------------------------------------------------
__global__ __launch_bounds__(256) void vtrans_kernel(
    const unsigned short* __restrict__ vh, unsigned short* __restrict__ vt)
{
  const int b = blockIdx.z;
  const int s0 = blockIdx.x * 64, n0 = blockIdx.y * 64;
  const int t = threadIdx.x;
  __shared__ unsigned short tl[64 * 72];
#pragma unroll
  for (int i = 0; i < 2; i++) {
    int f = t + 256 * i;
    int sr = f >> 3, c8 = (f & 7) * 8;
    uint4 raw = *(const uint4*)&vh[((size_t)b * SEQ + s0 + sr) * DIM + n0 + c8];
    unsigned short u[8];
    *(uint4*)u = raw;
#pragma unroll
    for (int j = 0; j < 8; j++) tl[(c8 + j) * 72 + sr] = u[j];
  }
  __syncthreads();
#pragma unroll
  for (int i = 0; i < 2; i++) {
    int f = t + 256 * i;
    int nr = f >> 3, s8 = (f & 7) * 8;
    *(uint4*)&vt[((size_t)b * DIM + n0 + nr) * SEQ + s0 + s8] = *(const uint4*)&tl[nr * 72 + s8];
  }
}

// ---------------------------------------------------------------------------
// flash: 512 threads. Group g = waves 4g..4g+3 processes keys [g*1024, +1024).
// Transposed compute: S^T = K Q^T (A=K rows, B=Q rows), O^T = V^T P^T
// (A=vt rows, B=P^T rows). Softmax state per-lane scalar (qrow = lane&15).
// Staging: 128 keys x 128 dims chunks (32 KiB/group), xor-16 swizzle.
// End: split-K merge via LDS (m/l exchange + alpha-scaled O add), coalesced out.
// ---------------------------------------------------------------------------
__global__ __launch_bounds__(512, 2) void flash_kernel(
    const unsigned short* __restrict__ Qb, const unsigned short* __restrict__ Kb,
    const unsigned short* __restrict__ Vtb, float* __restrict__ Ob)
{
  const int zb = blockIdx.x & 7;          // batch -> XCD affinity
  const int q0 = (blockIdx.x >> 3) * 64;  // q-tile base row
  const unsigned short* Q = Qb + (size_t)zb * SEQ * DIM;
  const unsigned short* K = Kb + (size_t)zb * SEQ * DIM;
  const unsigned short* V = Vtb + (size_t)zb * DIM * SEQ;  // [d][s]
  float* Out = Ob + (size_t)zb * SEQ * DIM;

  const int t = threadIdx.x;
  const int lane = t & 63;
  const int wg = (t >> 6) & 3;  // wave within group
  const int g = t >> 8;         // split-K group (0 or 1)
  const int tg = t & 255;       // thread within group
  const int lr = lane & 15, lq4 = lane >> 4;
  const float L2E = 1.4426950408889634f;

  __shared__ unsigned short sm[50176];  // KV[2] 32K+32K | Pb[2] 17K+17K
  __shared__ float ml[2][64][2];
  unsigned short* KV = sm + g * 16384;         // [128 rows][128 halves], xor16
  unsigned short* Pb = sm + 32768 + g * 8704;  // P^T [64 qrow][136]
  float* Obuf = (float*)sm;                    // epilogue alias [64][132]

  // ---- Q B-frags direct from global: qf[ks] = Q[qrow][ks*32 + lq4*8 ..+8)
  const unsigned short* qp = &Q[(size_t)(q0 + 16 * wg + lr) * DIM + lq4 * 8];
  half8 qf[16];
#pragma unroll
  for (int ks = 0; ks < 16; ks++) qf[ks] = ld_frag(&qp[ks * 32]);

  f32x4 acc[32];
  const f32x4 zero = {0.f, 0.f, 0.f, 0.f};
#pragma unroll
  for (int ob = 0; ob < 32; ob++) acc[ob] = zero;
  float m_run = -__builtin_inff(), l_run = 0.f;

  for (int j = 0; j < 8; j++) {
    const int ktg = g * 8 + j;  // this group's key tile (128 keys)

    // ===== phase A: S^T[key][qrow] over 4 d-chunks of 128 =====
    f32x4 sacc[8];
#pragma unroll
    for (int c = 0; c < 8; c++) sacc[c] = zero;
#pragma unroll
    for (int dch = 0; dch < 4; dch++) {
      const int dst = dch * 128;
      __syncthreads();
#pragma unroll
      for (int i = 0; i < 8; i++) {
        int f = tg + 256 * i;
        int row = f >> 4, c16 = f & 15;
        int sc = c16 ^ (row & 15);
        gl_lds16(&K[(size_t)(ktg * 128 + row) * DIM + dst + sc * 8],
                 &KV[i * 2048 + wg * 512]);
      }
      __syncthreads();
#pragma unroll
      for (int ks2 = 0; ks2 < 4; ks2++) {
        half8 qb = qf[dch * 4 + ks2];
#pragma unroll
        for (int c = 0; c < 8; c++) {
          int row = 16 * c + lr;
          int p = ((ks2 << 2) + lq4) ^ lr;
          half8 kf = ld_frag(&KV[row * 128 + p * 8]);
          sacc[c] = __builtin_amdgcn_mfma_f32_16x16x32_f16(kf, qb, sacc[c], 0, 0, 0);
        }
      }
    }

    // ===== phase B: online softmax (per-lane scalar state; qrow = lr) =====
    float mx = sacc[0][0];
#pragma unroll
    for (int c = 0; c < 8; c++)
#pragma unroll
      for (int e = 0; e < 4; e++) mx = fmaxf(mx, sacc[c][e]);
    mx = fmaxf(mx, __shfl_xor(mx, 16, 64));
    mx = fmaxf(mx, __shfl_xor(mx, 32, 64));
    float mnew = fmaxf(m_run, mx);
    float alpha = exp2f((m_run - mnew) * L2E);
    m_run = mnew;

    float sum = 0.f;
#pragma unroll
    for (int c = 0; c < 8; c++) {
      float p0 = exp2f((sacc[c][0] - mnew) * L2E);
      float p1 = exp2f((sacc[c][1] - mnew) * L2E);
      float p2 = exp2f((sacc[c][2] - mnew) * L2E);
      float p3 = exp2f((sacc[c][3] - mnew) * L2E);
      sum += (p0 + p1) + (p2 + p3);
      ushort4 pk;
      pk.x = f2h(p0); pk.y = f2h(p1); pk.z = f2h(p2); pk.w = f2h(p3);
      // P^T[qrow][key]: key = 16c + lq4*4 + e  -> b64 write
      *(ushort4*)&Pb[(16 * wg + lr) * 136 + 16 * c + lq4 * 4] = pk;
    }
    sum += __shfl_xor(sum, 16, 64);
    sum += __shfl_xor(sum, 32, 64);
    l_run = alpha * l_run + sum;

#pragma unroll
    for (int ob = 0; ob < 32; ob++) {
      acc[ob][0] *= alpha; acc[ob][1] *= alpha;
      acc[ob][2] *= alpha; acc[ob][3] *= alpha;
    }

    // ===== phase C: O^T += V^T P^T (B-frags from own wave's Pb rows) =====
    half8 pf[4];
#pragma unroll
    for (int kc = 0; kc < 4; kc++)
      pf[kc] = ld_frag(&Pb[(16 * wg + lr) * 136 + kc * 32 + lq4 * 8]);
#pragma unroll
    for (int dch = 0; dch < 4; dch++) {
      const int dst = dch * 128;
      __syncthreads();
#pragma unroll
      for (int i = 0; i < 8; i++) {
        int f = tg + 256 * i;
        int row = f >> 4, c16 = f & 15;
        int sc = c16 ^ (row & 15);
        gl_lds16(&V[(size_t)(dst + row) * SEQ + ktg * 128 + sc * 8],
                 &KV[i * 2048 + wg * 512]);
      }
      __syncthreads();
#pragma unroll
      for (int c = 0; c < 8; c++) {
        int row = 16 * c + lr;
#pragma unroll
        for (int kc = 0; kc < 4; kc++) {
          int p = ((kc << 2) + lq4) ^ lr;
          half8 vf = ld_frag(&KV[row * 128 + p * 8]);
          acc[dch * 8 + c] =
              __builtin_amdgcn_mfma_f32_16x16x32_f16(vf, pf[kc], acc[dch * 8 + c], 0, 0, 0);
        }
      }
    }
  }

  // ===== split-K merge + output =====
  if (lq4 == 0) {
    ml[g][16 * wg + lr][0] = m_run;
    ml[g][16 * wg + lr][1] = l_run;
  }
  __syncthreads();
  const int qrow = 16 * wg + lr;
  float m0 = ml[0][qrow][0], l0 = ml[0][qrow][1];
  float m1 = ml[1][qrow][0], l1 = ml[1][qrow][1];
  float mM = fmaxf(m0, m1);
  float a0 = exp2f((m0 - mM) * L2E), a1 = exp2f((m1 - mM) * L2E);
  float inv = 1.0f / (a0 * l0 + a1 * l1);
  float myscale = (g == 0) ? a0 : a1;

#pragma unroll
  for (int dch = 0; dch < 4; dch++) {
    __syncthreads();
    if (g == 1) {
#pragma unroll
      for (int c = 0; c < 8; c++) {
        f32x4 v = acc[dch * 8 + c];
        float4 w; w.x = v[0] * myscale; w.y = v[1] * myscale;
        w.z = v[2] * myscale; w.w = v[3] * myscale;
        *(float4*)&Obuf[qrow * 132 + 16 * c + lq4 * 4] = w;
      }
    }
    __syncthreads();
    if (g == 0) {
#pragma unroll
      for (int c = 0; c < 8; c++) {
        f32x4 v = acc[dch * 8 + c];
        float4 r = *(const float4*)&Obuf[qrow * 132 + 16 * c + lq4 * 4];
        float4 w;
        w.x = (v[0] * myscale + r.x) * inv;
        w.y = (v[1] * myscale + r.y) * inv;
        w.z = (v[2] * myscale + r.z) * inv;
        w.w = (v[3] * myscale + r.w) * inv;
        *(float4*)&Obuf[qrow * 132 + 16 * c + lq4 * 4] = w;
      }
    }
    __syncthreads();
#pragma unroll
    for (int i = 0; i < 4; i++) {
      int idx = t + 512 * i;
      int row = idx >> 5, c4 = (idx & 31) * 4;
      *(float4*)&Out[(size_t)(q0 + row) * DIM + dch * 128 + c4] =
          *(const float4*)&Obuf[row * 132 + c4];
    }
  }
}

// ---------------------------------------------------------------------------
extern "C" void kernel_launch(void* const* d_in, const int* in_sizes, int n_in,
                              void* d_out, int out_size, void* d_ws, size_t ws_size,
                              hipStream_t stream)
{
  const float* X  = (const float*)d_in[0];
  const float* Wq = (const float*)d_in[1];
  const float* bq = (const float*)d_in[2];
  const float* Wk = (const float*)d_in[3];
  const float* bk = (const float*)d_in[4];
  const float* Wv = (const float*)d_in[5];
  const float* bv = (const float*)d_in[6];
  float* Out = (float*)d_out;

  char* ws = (char*)d_ws;
  const size_t MB = 1u << 20;
  unsigned short* qh = (unsigned short*)(ws);            // 16 MiB
  unsigned short* kh = (unsigned short*)(ws + 16 * MB);  // 16 MiB (proj z=1)
  unsigned short* vh = (unsigned short*)(ws + 32 * MB);  // 16 MiB (proj z=2)
  unsigned short* vt = (unsigned short*)(ws + 48 * MB);  // 16 MiB
  unsigned short* xh = (unsigned short*)(ws + 48 * MB);  // alias vt: dead pre-vtrans
  unsigned short* Wt = (unsigned short*)(ws + 64 * MB);  // 1.5 MiB

  cvt_x_kernel<<<dim3(BSZ * DIM / 2048), 256, 0, stream>>>(X, xh);
  cvt_w_kernel<<<dim3(8, 8, 3), 256, 0, stream>>>(Wq, Wk, Wv, Wt);
  proj_kernel<<<dim3(BSZ / 128, DIM / 128, 3), 256, 0, stream>>>(
      xh, Wt, bq, bk, bv, qh);
  vtrans_kernel<<<dim3(SEQ / 64, DIM / 64, NB), 256, 0, stream>>>(vh, vt);
  flash_kernel<<<dim3(NB * SEQ / 64), 512, 0, stream>>>(qh, kh, vt, Out);
}

// Round 7
// 385.770 us; speedup vs baseline: 1.0712x; 1.0712x over previous
//
#include <hip/hip_runtime.h>
#include <cstdint>
#include <cstddef>

// SelfAttention: B=8, S=2048, D=512, fp32 in/out.
// R7: R6 flash structure (8 waves, split-K x2, transposed S^T/O^T, xor-16
// swizzle) with the spill fixed: Q lives in LDS (not 64 VGPRs/wave), Pb
// aliases the KV staging region. Per-wave budget ~220 regs < 256 cap.
// ws: [qh 16M][kh 16M][vh 16M][vt 16M (xh aliases)][Wt 1.5M] = 65.5 MiB.

#define SEQ 2048
#define DIM 512
#define NB 8
#define BSZ (NB * SEQ)

typedef __attribute__((ext_vector_type(8))) _Float16 half8;
typedef __attribute__((ext_vector_type(4))) float f32x4;

__device__ __forceinline__ unsigned short f2h(float f) {
  _Float16 h = (_Float16)f;
  return __builtin_bit_cast(unsigned short, h);
}
__device__ __forceinline__ half8 ld_frag(const unsigned short* p) {
  return *(const half8*)(const void*)p;
}
__device__ __forceinline__ void gl_lds16(const unsigned short* g, unsigned short* l) {
  __builtin_amdgcn_global_load_lds(
      (__attribute__((address_space(1))) void*)g,
      (__attribute__((address_space(3))) void*)l, 16, 0, 0);
}

// ---------------------------------------------------------------------------
__global__ __launch_bounds__(256) void cvt_x_kernel(
    const float* __restrict__ X, unsigned short* __restrict__ xh)
{
  size_t i0 = ((size_t)blockIdx.x * 256 + threadIdx.x) * 8;
  float4 a = *(const float4*)&X[i0];
  float4 b = *(const float4*)&X[i0 + 4];
  ushort4 o0; o0.x = f2h(a.x); o0.y = f2h(a.y); o0.z = f2h(a.z); o0.w = f2h(a.w);
  ushort4 o1; o1.x = f2h(b.x); o1.y = f2h(b.y); o1.z = f2h(b.z); o1.w = f2h(b.w);
  *(ushort4*)&xh[i0] = o0;
  *(ushort4*)&xh[i0 + 4] = o1;
}

// ---------------------------------------------------------------------------
__global__ __launch_bounds__(256) void cvt_w_kernel(
    const float* __restrict__ Wq, const float* __restrict__ Wk,
    const float* __restrict__ Wv, unsigned short* __restrict__ Wt)
{
  const int z = blockIdx.z;
  const float* W = (z == 0) ? Wq : (z == 1) ? Wk : Wv;
  unsigned short* out = Wt + (size_t)z * DIM * DIM;
  const int k0 = blockIdx.x * 64, n0 = blockIdx.y * 64;
  const int t = threadIdx.x;
  __shared__ unsigned short tl[64 * 72];
#pragma unroll
  for (int i = 0; i < 4; i++) {
    int f = t + 256 * i;
    int kr = f >> 4, c4 = (f & 15) * 4;
    float4 v = *(const float4*)&W[(size_t)(k0 + kr) * DIM + n0 + c4];
    tl[(c4 + 0) * 72 + kr] = f2h(v.x);
    tl[(c4 + 1) * 72 + kr] = f2h(v.y);
    tl[(c4 + 2) * 72 + kr] = f2h(v.z);
    tl[(c4 + 3) * 72 + kr] = f2h(v.w);
  }
  __syncthreads();
#pragma unroll
  for (int i = 0; i < 2; i++) {
    int f = t + 256 * i;
    int nr = f >> 3, k8 = (f & 7) * 8;
    *(uint4*)&out[(size_t)(n0 + nr) * DIM + k0 + k8] = *(const uint4*)&tl[nr * 72 + k8];
  }
}

// ---------------------------------------------------------------------------
// proj (unchanged, validated): qkv[z] = fp16(xh @ Wt[z]^T + b[z]).
// ---------------------------------------------------------------------------
__global__ __launch_bounds__(256) void proj_kernel(
    const unsigned short* __restrict__ xh, const unsigned short* __restrict__ Wt,
    const float* __restrict__ bq, const float* __restrict__ bk,
    const float* __restrict__ bv, unsigned short* __restrict__ outbase)
{
  const int z = blockIdx.z;
  const unsigned short* Wz = Wt + (size_t)z * DIM * DIM;
  const float* bias = (z == 0) ? bq : (z == 1) ? bk : bv;
  unsigned short* out = outbase + (size_t)z * BSZ * DIM;
  const int m0 = blockIdx.x * 128, n0 = blockIdx.y * 128;
  const int t = threadIdx.x, lane = t & 63, wave = t >> 6;
  const int wrow = (wave >> 1) * 64, wcol = (wave & 1) * 64;
  const int lr = lane & 15, lq = (lane >> 4) * 8;

  __shared__ unsigned short sm[128 * 132];
  unsigned short* As = sm;
  unsigned short* Bs = sm + 128 * 64;

  f32x4 acc[4][4];
  const f32x4 zero = {0.f, 0.f, 0.f, 0.f};
#pragma unroll
  for (int r = 0; r < 4; r++)
#pragma unroll
    for (int c = 0; c < 4; c++) acc[r][c] = zero;

  for (int k0 = 0; k0 < DIM; k0 += 64) {
    __syncthreads();
#pragma unroll
    for (int i = 0; i < 4; i++) {
      int f = t + 256 * i;
      int row = f >> 3, c8 = (f & 7) * 8;
      gl_lds16(&xh[(size_t)(m0 + row) * DIM + k0 + c8], &As[i * 2048 + wave * 512]);
      gl_lds16(&Wz[(size_t)(n0 + row) * DIM + k0 + c8], &Bs[i * 2048 + wave * 512]);
    }
    __syncthreads();
#pragma unroll
    for (int kk = 0; kk < 64; kk += 32) {
      half8 a[4], b[4];
#pragma unroll
      for (int r = 0; r < 4; r++) a[r] = ld_frag(&As[(wrow + 16 * r + lr) * 64 + kk + lq]);
#pragma unroll
      for (int c = 0; c < 4; c++) b[c] = ld_frag(&Bs[(wcol + 16 * c + lr) * 64 + kk + lq]);
#pragma unroll
      for (int r = 0; r < 4; r++)
#pragma unroll
        for (int c = 0; c < 4; c++)
          acc[r][c] = __builtin_amdgcn_mfma_f32_16x16x32_f16(a[r], b[c], acc[r][c], 0, 0, 0);
    }
  }
  __syncthreads();
#pragma unroll
  for (int c = 0; c < 4; c++) {
    float bb = bias[n0 + wcol + 16 * c + lr];
#pragma unroll
    for (int r = 0; r < 4; r++)
#pragma unroll
      for (int e = 0; e < 4; e++)
        sm[(wrow + 16 * r + (lane >> 4) * 4 + e) * 132 + wcol + 16 * c + lr] =
            f2h(acc[r][c][e] + bb);
  }
  __syncthreads();
#pragma unroll
  for (int i = 0; i < 8; i++) {
    int f = t + 256 * i;
    int row = f >> 4, c8 = (f & 15) * 8;
    *(uint4*)&out[(size_t)(m0 + row) * DIM + n0 + c8] = *(const uint4*)&sm[row * 132 + c8];
  }
}

// ---------------------------------------------------------------------------
__global__ __launch_bounds__(256) void vtrans_kernel(
    const unsigned short* __restrict__ vh, unsigned short* __restrict__ vt)
{
  const int b = blockIdx.z;
  const int s0 = blockIdx.x * 64, n0 = blockIdx.y * 64;
  const int t = threadIdx.x;
  __shared__ unsigned short tl[64 * 72];
#pragma unroll
  for (int i = 0; i < 2; i++) {
    int f = t + 256 * i;
    int sr = f >> 3, c8 = (f & 7) * 8;
    uint4 raw = *(const uint4*)&vh[((size_t)b * SEQ + s0 + sr) * DIM + n0 + c8];
    unsigned short u[8];
    *(uint4*)u = raw;
#pragma unroll
    for (int j = 0; j < 8; j++) tl[(c8 + j) * 72 + sr] = u[j];
  }
  __syncthreads();
#pragma unroll
  for (int i = 0; i < 2; i++) {
    int f = t + 256 * i;
    int nr = f >> 3, s8 = (f & 7) * 8;
    *(uint4*)&vt[((size_t)b * DIM + n0 + nr) * SEQ + s0 + s8] = *(const uint4*)&tl[nr * 72 + s8];
  }
}

// ---------------------------------------------------------------------------
// flash R7: 512 threads, split-K x2 (groups of 4 waves), transposed compute.
// Q in LDS (staged once, xor-16). Pb aliases the group's KV staging region
// (lifetime: phase-B write -> pf read; barriers protect). No persistent
// register arrays besides acc (AGPR) => no spills.
// ---------------------------------------------------------------------------
__global__ __launch_bounds__(512, 2) void flash_kernel(
    const unsigned short* __restrict__ Qb, const unsigned short* __restrict__ Kb,
    const unsigned short* __restrict__ Vtb, float* __restrict__ Ob)
{
  const int zb = blockIdx.x & 7;          // batch -> XCD affinity
  const int q0 = (blockIdx.x >> 3) * 64;  // q-tile base row
  const unsigned short* Q = Qb + (size_t)zb * SEQ * DIM;
  const unsigned short* K = Kb + (size_t)zb * SEQ * DIM;
  const unsigned short* V = Vtb + (size_t)zb * DIM * SEQ;  // [d][s]
  float* Out = Ob + (size_t)zb * SEQ * DIM;

  const int t = threadIdx.x;
  const int lane = t & 63;
  const int wave = t >> 6;
  const int wg = wave & 3;      // wave within group
  const int g = t >> 8;         // split-K group (0 or 1)
  const int tg = t & 255;       // thread within group
  const int lr = lane & 15, lq4 = lane >> 4;
  const float L2E = 1.4426950408889634f;

  __shared__ unsigned short sm[65536];  // [KV g0 32KB][KV g1 32KB][Qlds 64KB]
  __shared__ float ml[2][64][2];
  unsigned short* KV = sm + g * 16384;    // [128 rows][128 halves], xor-16
  unsigned short* Pb = sm + g * 16384;    // aliases KV (barrier-protected)
  unsigned short* Qlds = sm + 32768;      // [64 rows][512 halves], xor-16
  float* Obuf = (float*)sm;               // epilogue alias [64][132]

  // ---- stage Q once: 64 rows x 512 halves (xor-16 swizzle on 8-half chunks)
#pragma unroll
  for (int i = 0; i < 8; i++) {
    int f = t + 512 * i;
    int row = f >> 6, c64 = f & 63;
    int lc = c64 ^ (row & 15);
    gl_lds16(&Q[(size_t)(q0 + row) * DIM + lc * 8], &Qlds[i * 4096 + wave * 512]);
  }

  f32x4 acc[32];
  const f32x4 zero = {0.f, 0.f, 0.f, 0.f};
#pragma unroll
  for (int ob = 0; ob < 32; ob++) acc[ob] = zero;
  float m_run = -__builtin_inff(), l_run = 0.f;

  for (int j = 0; j < 8; j++) {
    const int ktg = g * 8 + j;  // this group's key tile (128 keys)

    // ===== phase A: S^T[key][qrow] over 4 d-chunks of 128 =====
    f32x4 sacc[8];
#pragma unroll
    for (int c = 0; c < 8; c++) sacc[c] = zero;
#pragma unroll
    for (int dch = 0; dch < 4; dch++) {
      const int dst = dch * 128;
      __syncthreads();
#pragma unroll
      for (int i = 0; i < 8; i++) {
        int f = tg + 256 * i;
        int row = f >> 4, c16 = f & 15;
        int sc = c16 ^ (row & 15);
        gl_lds16(&K[(size_t)(ktg * 128 + row) * DIM + dst + sc * 8],
                 &KV[i * 2048 + wg * 512]);
      }
      __syncthreads();
      half8 qb4[4];
#pragma unroll
      for (int ks2 = 0; ks2 < 4; ks2++)
        qb4[ks2] = ld_frag(
            &Qlds[(16 * wg + lr) * 512 + ((dch * 16 + ks2 * 4 + lq4) ^ lr) * 8]);
#pragma unroll
      for (int ks2 = 0; ks2 < 4; ks2++) {
#pragma unroll
        for (int c = 0; c < 8; c++) {
          int row = 16 * c + lr;
          int p = ((ks2 << 2) + lq4) ^ lr;
          half8 kf = ld_frag(&KV[row * 128 + p * 8]);
          sacc[c] = __builtin_amdgcn_mfma_f32_16x16x32_f16(kf, qb4[ks2], sacc[c], 0, 0, 0);
        }
      }
    }
    __syncthreads();  // all K-frag reads done; KV region may now host Pb

    // ===== phase B: online softmax (per-lane scalar state; qrow = lr) =====
    float mx = sacc[0][0];
#pragma unroll
    for (int c = 0; c < 8; c++)
#pragma unroll
      for (int e = 0; e < 4; e++) mx = fmaxf(mx, sacc[c][e]);
    mx = fmaxf(mx, __shfl_xor(mx, 16, 64));
    mx = fmaxf(mx, __shfl_xor(mx, 32, 64));
    float mnew = fmaxf(m_run, mx);
    float alpha = exp2f((m_run - mnew) * L2E);
    m_run = mnew;

    float sum = 0.f;
#pragma unroll
    for (int c = 0; c < 8; c++) {
      float p0 = exp2f((sacc[c][0] - mnew) * L2E);
      float p1 = exp2f((sacc[c][1] - mnew) * L2E);
      float p2 = exp2f((sacc[c][2] - mnew) * L2E);
      float p3 = exp2f((sacc[c][3] - mnew) * L2E);
      sum += (p0 + p1) + (p2 + p3);
      ushort4 pk;
      pk.x = f2h(p0); pk.y = f2h(p1); pk.z = f2h(p2); pk.w = f2h(p3);
      *(ushort4*)&Pb[(16 * wg + lr) * 136 + 16 * c + lq4 * 4] = pk;
    }
    sum += __shfl_xor(sum, 16, 64);
    sum += __shfl_xor(sum, 32, 64);
    l_run = alpha * l_run + sum;

    // pf: B-frags of P^T for this wave's 16 q-rows (same-wave data; lgkmcnt only)
    half8 pf[4];
#pragma unroll
    for (int kc = 0; kc < 4; kc++)
      pf[kc] = ld_frag(&Pb[(16 * wg + lr) * 136 + kc * 32 + lq4 * 8]);

#pragma unroll
    for (int ob = 0; ob < 32; ob++) {
      acc[ob][0] *= alpha; acc[ob][1] *= alpha;
      acc[ob][2] *= alpha; acc[ob][3] *= alpha;
    }

    // ===== phase C: O^T += V^T P^T =====
#pragma unroll
    for (int dch = 0; dch < 4; dch++) {
      const int dst = dch * 128;
      __syncthreads();  // also ensures all pf reads done before V clobbers Pb
#pragma unroll
      for (int i = 0; i < 8; i++) {
        int f = tg + 256 * i;
        int row = f >> 4, c16 = f & 15;
        int sc = c16 ^ (row & 15);
        gl_lds16(&V[(size_t)(dst + row) * SEQ + ktg * 128 + sc * 8],
                 &KV[i * 2048 + wg * 512]);
      }
      __syncthreads();
#pragma unroll
      for (int c = 0; c < 8; c++) {
        int row = 16 * c + lr;
#pragma unroll
        for (int kc = 0; kc < 4; kc++) {
          int p = ((kc << 2) + lq4) ^ lr;
          half8 vf = ld_frag(&KV[row * 128 + p * 8]);
          acc[dch * 8 + c] =
              __builtin_amdgcn_mfma_f32_16x16x32_f16(vf, pf[kc], acc[dch * 8 + c], 0, 0, 0);
        }
      }
    }
  }

  // ===== split-K merge + output =====
  if (lq4 == 0) {
    ml[g][16 * wg + lr][0] = m_run;
    ml[g][16 * wg + lr][1] = l_run;
  }
  __syncthreads();
  const int qrow = 16 * wg + lr;
  float m0 = ml[0][qrow][0], l0 = ml[0][qrow][1];
  float m1 = ml[1][qrow][0], l1 = ml[1][qrow][1];
  float mM = fmaxf(m0, m1);
  float a0 = exp2f((m0 - mM) * L2E), a1 = exp2f((m1 - mM) * L2E);
  float inv = 1.0f / (a0 * l0 + a1 * l1);
  float myscale = (g == 0) ? a0 : a1;

#pragma unroll
  for (int dch = 0; dch < 4; dch++) {
    __syncthreads();
    if (g == 1) {
#pragma unroll
      for (int c = 0; c < 8; c++) {
        f32x4 v = acc[dch * 8 + c];
        float4 w; w.x = v[0] * myscale; w.y = v[1] * myscale;
        w.z = v[2] * myscale; w.w = v[3] * myscale;
        *(float4*)&Obuf[qrow * 132 + 16 * c + lq4 * 4] = w;
      }
    }
    __syncthreads();
    if (g == 0) {
#pragma unroll
      for (int c = 0; c < 8; c++) {
        f32x4 v = acc[dch * 8 + c];
        float4 r = *(const float4*)&Obuf[qrow * 132 + 16 * c + lq4 * 4];
        float4 w;
        w.x = (v[0] * myscale + r.x) * inv;
        w.y = (v[1] * myscale + r.y) * inv;
        w.z = (v[2] * myscale + r.z) * inv;
        w.w = (v[3] * myscale + r.w) * inv;
        *(float4*)&Obuf[qrow * 132 + 16 * c + lq4 * 4] = w;
      }
    }
    __syncthreads();
#pragma unroll
    for (int i = 0; i < 4; i++) {
      int idx = t + 512 * i;
      int row = idx >> 5, c4 = (idx & 31) * 4;
      *(float4*)&Out[(size_t)(q0 + row) * DIM + dch * 128 + c4] =
          *(const float4*)&Obuf[row * 132 + c4];
    }
  }
}

// ---------------------------------------------------------------------------
extern "C" void kernel_launch(void* const* d_in, const int* in_sizes, int n_in,
                              void* d_out, int out_size, void* d_ws, size_t ws_size,
                              hipStream_t stream)
{
  const float* X  = (const float*)d_in[0];
  const float* Wq = (const float*)d_in[1];
  const float* bq = (const float*)d_in[2];
  const float* Wk = (const float*)d_in[3];
  const float* bk = (const float*)d_in[4];
  const float* Wv = (const float*)d_in[5];
  const float* bv = (const float*)d_in[6];
  float* Out = (float*)d_out;

  char* ws = (char*)d_ws;
  const size_t MB = 1u << 20;
  unsigned short* qh = (unsigned short*)(ws);            // 16 MiB
  unsigned short* kh = (unsigned short*)(ws + 16 * MB);  // 16 MiB (proj z=1)
  unsigned short* vh = (unsigned short*)(ws + 32 * MB);  // 16 MiB (proj z=2)
  unsigned short* vt = (unsigned short*)(ws + 48 * MB);  // 16 MiB
  unsigned short* xh = (unsigned short*)(ws + 48 * MB);  // alias vt: dead pre-vtrans
  unsigned short* Wt = (unsigned short*)(ws + 64 * MB);  // 1.5 MiB

  cvt_x_kernel<<<dim3(BSZ * DIM / 2048), 256, 0, stream>>>(X, xh);
  cvt_w_kernel<<<dim3(8, 8, 3), 256, 0, stream>>>(Wq, Wk, Wv, Wt);
  proj_kernel<<<dim3(BSZ / 128, DIM / 128, 3), 256, 0, stream>>>(
      xh, Wt, bq, bk, bv, qh);
  vtrans_kernel<<<dim3(SEQ / 64, DIM / 64, NB), 256, 0, stream>>>(vh, vt);
  flash_kernel<<<dim3(NB * SEQ / 64), 512, 0, stream>>>(qh, kh, vt, Out);
}